// Round 1
// baseline (2157.251 us; speedup 1.0000x reference)
//
#include <hip/hip_runtime.h>

#define NPB 64  // nodes per block in node_gemm

// ---------------- CSR build ----------------
__global__ void count_kernel(const int* __restrict__ from_idx, const int* __restrict__ to_idx,
                             int* __restrict__ cnt_to, int* __restrict__ cnt_from, int E) {
    int e = blockIdx.x * blockDim.x + threadIdx.x;
    if (e >= E) return;
    atomicAdd(&cnt_to[to_idx[e]], 1);
    atomicAdd(&cnt_from[from_idx[e]], 1);
}

__global__ void scan_kernel(const int* __restrict__ cnt, int* __restrict__ off,
                            int* __restrict__ cursor, int n) {
    __shared__ int part[1024];
    int tid = threadIdx.x;
    int chunk = (n + 1023) >> 10;
    int beg = tid * chunk, end = min(beg + chunk, n);
    int s = 0;
    for (int i = beg; i < end; ++i) s += cnt[i];
    part[tid] = s;
    __syncthreads();
    for (int d = 1; d < 1024; d <<= 1) {
        int v = part[tid];
        int add = (tid >= d) ? part[tid - d] : 0;
        __syncthreads();
        part[tid] = v + add;
        __syncthreads();
    }
    int base = part[tid] - s;  // exclusive prefix of this thread's chunk
    for (int i = beg; i < end; ++i) {
        off[i] = base; cursor[i] = base; base += cnt[i];
    }
    if (tid == 1023) off[n] = part[1023];
}

__global__ void fill_kernel(const int* __restrict__ from_idx, const int* __restrict__ to_idx,
                            int* __restrict__ cur_to, int* __restrict__ cur_from,
                            int* __restrict__ list_to, int* __restrict__ list_from, int E) {
    int e = blockIdx.x * blockDim.x + threadIdx.x;
    if (e >= E) return;
    int f = from_idx[e], t = to_idx[e];
    int p = atomicAdd(&cur_to[t], 1);
    list_to[p] = f;            // store SOURCE node directly (we never need edge id)
    int q = atomicAdd(&cur_from[f], 1);
    list_from[q] = t;
}

// ---------------- weight transposes (GRU uses x @ W.T) ----------------
__global__ void transpose_wih(const float* __restrict__ Wih, float* __restrict__ WihT) {
    int idx = blockIdx.x * 256 + threadIdx.x;  // 3*96*96
    if (idx >= 3 * 96 * 96) return;
    int l = idx / 9216, r = idx % 9216;
    int j = r / 96, k = r % 96;               // WihT[l][j][k] = Wih[l][k][j]
    WihT[idx] = Wih[l * 9216 + k * 96 + j];
}
__global__ void transpose_whh(const float* __restrict__ Whh, float* __restrict__ WhhT) {
    int idx = blockIdx.x * 256 + threadIdx.x;  // 3*32*96
    if (idx >= 3 * 32 * 96) return;
    int l = idx / 3072, r = idx % 3072;
    int j = r / 96, k = r % 96;               // WhhT[l][j][k] = Whh[l][k][j], j<32
    WhhT[idx] = Whh[l * 3072 + k * 32 + j];
}

// ---------------- generic node-wise GEMM: OUT[N,KO] (=|+=) IN[N,KI]@W[KI,KO] ----------------
// MODE 0: write + bias; MODE 1: write, no bias; MODE 2: accumulate += acc + degF*b2 + degR*rb2
template <int KI, int KO, int MODE>
__global__ void __launch_bounds__(256) node_gemm(
    const float* __restrict__ IN, int ldin, int coloff,
    const float* __restrict__ W, const float* __restrict__ bias,
    float* __restrict__ OUT,
    const int* __restrict__ offF, const int* __restrict__ offR,
    const float* __restrict__ b2, const float* __restrict__ rb2, int N)
{
    constexpr int KPW = KO / 4;                 // outputs per thread (4 waves cover KO)
    __shared__ float tile[NPB][KI + 1];         // +1 pad: 2-way bank alias only (free)
    int n0 = blockIdx.x * NPB;
    int tid = threadIdx.x;
    for (int idx = tid; idx < NPB * KI; idx += 256) {
        int r = idx / KI, c = idx % KI;
        int n = n0 + r;
        tile[r][c] = (n < N) ? IN[(long)n * ldin + coloff + c] : 0.f;
    }
    __syncthreads();
    int lane = tid & 63, w = tid >> 6;
    float acc[KPW];
#pragma unroll
    for (int c = 0; c < KPW; ++c) acc[c] = 0.f;
    const float* Wp = W + w * KPW;              // wave-uniform -> scalar loads
#pragma unroll 4
    for (int j = 0; j < KI; ++j) {
        float a = tile[lane][j];
#pragma unroll
        for (int c = 0; c < KPW; ++c) acc[c] = fmaf(a, Wp[j * KO + c], acc[c]);
    }
    int n = n0 + lane;
    if (n >= N) return;
    float* outp = OUT + (long)n * KO + w * KPW;
    if (MODE == 0) {
#pragma unroll
        for (int c = 0; c < KPW; ++c) outp[c] = acc[c] + bias[w * KPW + c];
    } else if (MODE == 1) {
#pragma unroll
        for (int c = 0; c < KPW; ++c) outp[c] = acc[c];
    } else {
        float dF = (float)(offF[n + 1] - offF[n]);
        float dR = (float)(offR[n + 1] - offR[n]);
#pragma unroll
        for (int c = 0; c < KPW; ++c)
            outp[c] += acc[c] + dF * b2[w * KPW + c] + dR * rb2[w * KPW + c];
    }
}

// ---------------- edge aggregation: one wave per node, CSR, no atomics ----------------
// hidden_e = relu(Pa[src] + Pb[n] + b1); PbAgg row n is overwritten with sum(hidden) (in-place safe:
// gathers touch only Pa; each wave reads its own Pb row before writing it).
__global__ void __launch_bounds__(256) agg_kernel(
    const int* __restrict__ off, const int* __restrict__ list,
    const float* __restrict__ Pa, float* PbAgg,
    const float* __restrict__ b1, int N)
{
    int n = (blockIdx.x * 256 + threadIdx.x) >> 6;  // global wave id = node
    int lane = threadIdx.x & 63;
    if (n >= N) return;
    float s0 = PbAgg[(long)n * 96 + lane] + b1[lane];
    float s1 = (lane < 32) ? (PbAgg[(long)n * 96 + 64 + lane] + b1[64 + lane]) : 0.f;
    float a0 = 0.f, a1 = 0.f;
    int beg = off[n], end = off[n + 1];
#pragma unroll 2
    for (int i = beg; i < end; ++i) {
        int src = list[i];                          // wave-uniform -> scalar load
        const float* p = Pa + (long)src * 96;
        float v0 = p[lane];
        float v1 = (lane < 32) ? p[64 + lane] : 0.f;
        a0 += fmaxf(v0 + s0, 0.f);
        a1 += fmaxf(v1 + s1, 0.f);                  // lanes>=32: 0, never stored
    }
    float* o = PbAgg + (long)n * 96;
    o[lane] = a0;
    if (lane < 32) o[64 + lane] = a1;
}

// ---------------- GRU gates ----------------
__global__ void gru_gates(const float* __restrict__ GI, const float* __restrict__ GH,
                          const float* __restrict__ h, float* __restrict__ hout, int N) {
    int idx = blockIdx.x * 256 + threadIdx.x;
    if (idx >= N * 32) return;
    int n = idx >> 5, k = idx & 31;
    const float* gi = GI + (long)n * 96;
    const float* gh = GH + (long)n * 96;
    float r = 1.f / (1.f + __expf(-(gi[k] + gh[k])));
    float z = 1.f / (1.f + __expf(-(gi[32 + k] + gh[32 + k])));
    float nn = tanhf(gi[64 + k] + r * gh[64 + k]);
    hout[idx] = (1.f - z) * nn + z * h[idx];
}

// ---------------- graph aggregator: gated transform + segmented sum (graph_idx sorted) ----------------
__global__ void graph_agg(const float* __restrict__ h, const float* __restrict__ W1,
                          const float* __restrict__ b1, const int* __restrict__ gidx,
                          float* __restrict__ gs, int N, int chunk) {
    int k = threadIdx.x;  // 128
    int n_start = blockIdx.x * chunk;
    if (n_start >= N) return;
    int n_end = min(n_start + chunk, N);
    float acc = 0.f;
    int cur = gidx[n_start];
    for (int n = n_start; n < n_end; ++n) {
        int g = gidx[n];
        if (g != cur) { atomicAdd(&gs[cur * 128 + k], acc); acc = 0.f; cur = g; }
        float g1 = b1[k], g2 = b1[128 + k];
#pragma unroll 8
        for (int j = 0; j < 32; ++j) {
            float hv = h[(long)n * 32 + j];        // block-uniform -> scalar load
            g1 = fmaf(hv, W1[j * 256 + k], g1);
            g2 = fmaf(hv, W1[j * 256 + 128 + k], g2);
        }
        acc += (1.f / (1.f + __expf(-g1))) * g2;
    }
    atomicAdd(&gs[cur * 128 + k], acc);
}

__global__ void final_gemm(const float* __restrict__ gs, const float* __restrict__ W,
                           const float* __restrict__ b, float* __restrict__ out) {
    int g = blockIdx.x, k = threadIdx.x;  // 128 threads
    float a = b[k];
#pragma unroll 8
    for (int j = 0; j < 128; ++j) a = fmaf(gs[g * 128 + j], W[j * 128 + k], a);
    out[g * 128 + k] = a;
}

extern "C" void kernel_launch(void* const* d_in, const int* in_sizes, int n_in,
                              void* d_out, int out_size, void* d_ws, size_t ws_size,
                              hipStream_t stream) {
    const float* node_features = (const float*)d_in[0];
    const float* enc_W  = (const float*)d_in[1];
    const float* enc_b  = (const float*)d_in[2];
    const float* msg_W1 = (const float*)d_in[3];
    const float* msg_b1 = (const float*)d_in[4];
    const float* msg_W2 = (const float*)d_in[5];
    const float* msg_b2 = (const float*)d_in[6];
    const float* rmsg_W1 = (const float*)d_in[7];
    const float* rmsg_b1 = (const float*)d_in[8];
    const float* rmsg_W2 = (const float*)d_in[9];
    const float* rmsg_b2 = (const float*)d_in[10];
    const float* gru_Wih = (const float*)d_in[11];
    const float* gru_Whh = (const float*)d_in[12];
    const float* gru_bih = (const float*)d_in[13];
    const float* gru_bhh = (const float*)d_in[14];
    const float* agg_W1 = (const float*)d_in[15];
    const float* agg_b1 = (const float*)d_in[16];
    const float* agg_W2 = (const float*)d_in[17];
    const float* agg_b2 = (const float*)d_in[18];
    const int* from_idx = (const int*)d_in[19];
    const int* to_idx   = (const int*)d_in[20];
    const int* graph_idx = (const int*)d_in[21];

    const int N = in_sizes[0] / 32;
    const int E = in_sizes[19];
    const int NG = out_size / 128;
    float* out = (float*)d_out;

    char* ws = (char*)d_ws;
    auto alloc = [&](size_t b) { void* p = (void*)ws; ws += (b + 255) & ~(size_t)255; return p; };
    int* cnt_to   = (int*)alloc((size_t)N * 4);
    int* cnt_from = (int*)alloc((size_t)N * 4);
    int* off_to   = (int*)alloc((size_t)(N + 1) * 4);
    int* off_from = (int*)alloc((size_t)(N + 1) * 4);
    int* cur_to   = (int*)alloc((size_t)N * 4);
    int* cur_from = (int*)alloc((size_t)N * 4);
    int* list_to  = (int*)alloc((size_t)E * 4);
    int* list_from= (int*)alloc((size_t)E * 4);
    float* h0  = (float*)alloc((size_t)N * 32 * 4);
    float* h1  = (float*)alloc((size_t)N * 32 * 4);
    float* PFa = (float*)alloc((size_t)N * 96 * 4);
    float* PFb = (float*)alloc((size_t)N * 96 * 4);
    float* PRa = (float*)alloc((size_t)N * 96 * 4);
    float* PRb = (float*)alloc((size_t)N * 96 * 4);
    float* WihT = (float*)alloc((size_t)3 * 96 * 96 * 4);
    float* WhhT = (float*)alloc((size_t)3 * 32 * 96 * 4);
    float* gs   = (float*)alloc((size_t)NG * 128 * 4);

    hipMemsetAsync(cnt_to, 0, (size_t)N * 4, stream);
    hipMemsetAsync(cnt_from, 0, (size_t)N * 4, stream);
    hipMemsetAsync(gs, 0, (size_t)NG * 128 * 4, stream);

    int gE = (E + 255) / 256;
    count_kernel<<<gE, 256, 0, stream>>>(from_idx, to_idx, cnt_to, cnt_from, E);
    scan_kernel<<<1, 1024, 0, stream>>>(cnt_to, off_to, cur_to, N);
    scan_kernel<<<1, 1024, 0, stream>>>(cnt_from, off_from, cur_from, N);
    fill_kernel<<<gE, 256, 0, stream>>>(from_idx, to_idx, cur_to, cur_from, list_to, list_from, E);

    transpose_wih<<<(3 * 96 * 96 + 255) / 256, 256, 0, stream>>>(gru_Wih, WihT);
    transpose_whh<<<(3 * 32 * 96 + 255) / 256, 256, 0, stream>>>(gru_Whh, WhhT);

    int gN64 = (N + 63) / 64;
    node_gemm<32, 32, 0><<<gN64, 256, 0, stream>>>(node_features, 32, 0, enc_W, enc_b, h0,
                                                   nullptr, nullptr, nullptr, nullptr, N);

    float* hcur = h0; float* hnext = h1;
    int gAgg = (N + 3) / 4;
    for (int l = 0; l < 3; ++l) {
        // projections: PFa=h@W1[:32], PFb=h@W1[32:], PRa=h@rW1[:32], PRb=h@rW1[32:]
        node_gemm<32, 96, 1><<<gN64, 256, 0, stream>>>(hcur, 32, 0, msg_W1 + l * 6144, nullptr, PFa, nullptr, nullptr, nullptr, nullptr, N);
        node_gemm<32, 96, 1><<<gN64, 256, 0, stream>>>(hcur, 32, 0, msg_W1 + l * 6144 + 3072, nullptr, PFb, nullptr, nullptr, nullptr, nullptr, N);
        node_gemm<32, 96, 1><<<gN64, 256, 0, stream>>>(hcur, 32, 0, rmsg_W1 + l * 6144, nullptr, PRa, nullptr, nullptr, nullptr, nullptr, N);
        node_gemm<32, 96, 1><<<gN64, 256, 0, stream>>>(hcur, 32, 0, rmsg_W1 + l * 6144 + 3072, nullptr, PRb, nullptr, nullptr, nullptr, nullptr, N);
        // aggregation (in-place: PFb -> sum of forward hiddens, PRb -> sum of reverse hiddens)
        agg_kernel<<<gAgg, 256, 0, stream>>>(off_to, list_to, PFa, PFb, msg_b1 + l * 96, N);
        agg_kernel<<<gAgg, 256, 0, stream>>>(off_from, list_from, PRa, PRb, rmsg_b1 + l * 96, N);
        // x = aggF@W2 + aggR@rW2 + degF*b2 + degR*rb2
        float* X = PFa;
        node_gemm<96, 96, 1><<<gN64, 256, 0, stream>>>(PFb, 96, 0, msg_W2 + l * 9216, nullptr, X, nullptr, nullptr, nullptr, nullptr, N);
        node_gemm<96, 96, 2><<<gN64, 256, 0, stream>>>(PRb, 96, 0, rmsg_W2 + l * 9216, nullptr, X, off_to, off_from, msg_b2 + l * 96, rmsg_b2 + l * 96, N);
        // GRU
        float* GI = PFb; float* GH = PRa;
        node_gemm<96, 96, 0><<<gN64, 256, 0, stream>>>(X, 96, 0, WihT + l * 9216, gru_bih + l * 96, GI, nullptr, nullptr, nullptr, nullptr, N);
        node_gemm<32, 96, 0><<<gN64, 256, 0, stream>>>(hcur, 32, 0, WhhT + l * 3072, gru_bhh + l * 96, GH, nullptr, nullptr, nullptr, nullptr, N);
        gru_gates<<<(N * 32 + 255) / 256, 256, 0, stream>>>(GI, GH, hcur, hnext, N);
        float* t = hcur; hcur = hnext; hnext = t;
    }

    graph_agg<<<(N + 63) / 64, 128, 0, stream>>>(hcur, agg_W1, agg_b1, graph_idx, gs, N, 64);
    final_gemm<<<NG, 128, 0, stream>>>(gs, agg_W2, agg_b2, out);
}

// Round 2
// 1937.097 us; speedup vs baseline: 1.1137x; 1.1137x over previous
//
#include <hip/hip_runtime.h>

// ---------------- CSR build (rank captured in count pass; fill is atomic-free) ----------------
__global__ void count_rank_kernel(const int* __restrict__ from_idx, const int* __restrict__ to_idx,
                                  int* __restrict__ cnt_to, int* __restrict__ cnt_from,
                                  int* __restrict__ rank_to, int* __restrict__ rank_from, int E) {
    int e = blockIdx.x * blockDim.x + threadIdx.x;
    if (e >= E) return;
    int f = from_idx[e], t = to_idx[e];
    rank_to[e] = atomicAdd(&cnt_to[t], 1);     // coalesced rank store
    rank_from[e] = atomicAdd(&cnt_from[f], 1);
}

__global__ void scan2_kernel(const int* __restrict__ cnt_to, int* __restrict__ off_to,
                             const int* __restrict__ cnt_from, int* __restrict__ off_from, int n) {
    const int* cnt = blockIdx.x ? cnt_from : cnt_to;
    int* off = blockIdx.x ? off_from : off_to;
    __shared__ int part[1024];
    int tid = threadIdx.x;
    int chunk = (n + 1023) >> 10;
    int beg = tid * chunk, end = min(beg + chunk, n);
    int s = 0;
    for (int i = beg; i < end; ++i) s += cnt[i];
    part[tid] = s;
    __syncthreads();
    for (int d = 1; d < 1024; d <<= 1) {
        int v = part[tid];
        int add = (tid >= d) ? part[tid - d] : 0;
        __syncthreads();
        part[tid] = v + add;
        __syncthreads();
    }
    int base = part[tid] - s;
    for (int i = beg; i < end; ++i) { off[i] = base; base += cnt[i]; }
    if (tid == 1023) off[n] = part[1023];
}

__global__ void fill_kernel(const int* __restrict__ from_idx, const int* __restrict__ to_idx,
                            const int* __restrict__ off_to, const int* __restrict__ off_from,
                            const int* __restrict__ rank_to, const int* __restrict__ rank_from,
                            int* __restrict__ list_to, int* __restrict__ list_from, int E) {
    int e = blockIdx.x * blockDim.x + threadIdx.x;
    if (e >= E) return;
    int f = from_idx[e], t = to_idx[e];
    list_to[off_to[t] + rank_to[e]] = f;       // pure scatter, no atomic dependency
    list_from[off_from[f] + rank_from[e]] = t;
}

// ---------------- weight transposes, one launch (GRU uses x @ W.T) ----------------
__global__ void transpose_all(const float* __restrict__ Wih, const float* __restrict__ Whh,
                              float* __restrict__ WihT, float* __restrict__ WhhT) {
    int idx = blockIdx.x * 256 + threadIdx.x;
    if (idx < 3 * 96 * 96) {
        int l = idx / 9216, r = idx % 9216;
        int j = r / 96, k = r % 96;            // WihT[l][j][k] = Wih[l][k][j]
        WihT[idx] = Wih[l * 9216 + k * 96 + j];
    } else if (idx < 3 * 96 * 96 + 3 * 32 * 96) {
        int i2 = idx - 3 * 96 * 96;
        int l = i2 / 3072, r = i2 % 3072;
        int j = r / 96, k = r % 96;            // WhhT[l][j][k] = Whh[l][k][j], j<32
        WhhT[i2] = Whh[l * 3072 + k * 32 + j];
    }
}

// ---------------- encoder: OUT[N,32] = IN[N,32]@W + b ----------------
__global__ void __launch_bounds__(256) enc_gemm(const float* __restrict__ IN,
                                                const float* __restrict__ W, const float* __restrict__ bias,
                                                float* __restrict__ OUT, int N) {
    __shared__ float tile[64][33];
    int n0 = blockIdx.x * 64, tid = threadIdx.x;
    for (int idx = tid; idx < 64 * 32; idx += 256) {
        int r = idx >> 5, c = idx & 31;
        int n = n0 + r;
        tile[r][c] = (n < N) ? IN[(long)n * 32 + c] : 0.f;
    }
    __syncthreads();
    int lane = tid & 63, w = tid >> 6;
    float acc[8] = {0};
    const float* Wp = W + w * 8;
#pragma unroll
    for (int j = 0; j < 32; ++j) {
        float a = tile[lane][j];
#pragma unroll
        for (int c = 0; c < 8; ++c) acc[c] = fmaf(a, Wp[j * 32 + c], acc[c]);
    }
    int n = n0 + lane;
    if (n >= N) return;
    float* outp = OUT + (long)n * 32 + w * 8;
#pragma unroll
    for (int c = 0; c < 8; ++c) outp[c] = acc[c] + bias[w * 8 + c];
}

// ---------------- fused projections: [Pa|Pb] = h @ [W1[0:32];W1[32:64]]  (y: fwd/rev) ----------------
__global__ void __launch_bounds__(256) proj_kernel(
    const float* __restrict__ h,
    const float* __restrict__ W1f, const float* __restrict__ W1r,
    float* __restrict__ PaF, float* __restrict__ PbF,
    float* __restrict__ PaR, float* __restrict__ PbR, int N)
{
    const float* W1 = blockIdx.y ? W1r : W1f;
    float* Pa = blockIdx.y ? PaR : PaF;
    float* Pb = blockIdx.y ? PbR : PbF;
    __shared__ float tile[64][33];
    int n0 = blockIdx.x * 64, tid = threadIdx.x;
    for (int idx = tid; idx < 64 * 32; idx += 256) {
        int r = idx >> 5, c = idx & 31;
        int n = n0 + r;
        tile[r][c] = (n < N) ? h[(long)n * 32 + c] : 0.f;
    }
    __syncthreads();
    int lane = tid & 63, w = tid >> 6;
    int c0 = w * 48;                            // waves 0,1 -> Pa cols; 2,3 -> Pb cols
    const float* Wp = (c0 < 96) ? (W1 + c0) : (W1 + 32 * 96 + (c0 - 96));
    float acc[48];
#pragma unroll
    for (int c = 0; c < 48; ++c) acc[c] = 0.f;
#pragma unroll 4
    for (int j = 0; j < 32; ++j) {
        float a = tile[lane][j];
#pragma unroll
        for (int c = 0; c < 48; ++c) acc[c] = fmaf(a, Wp[j * 96 + c], acc[c]);
    }
    int n = n0 + lane;
    if (n >= N) return;
    float* outp = (c0 < 96) ? (Pa + (long)n * 96 + c0) : (Pb + (long)n * 96 + (c0 - 96));
#pragma unroll
    for (int c = 0; c < 48; ++c) outp[c] = acc[c];
}

// ---------------- edge aggregation: one wave per node, float2 lanes, both dirs (y) ----------------
__global__ void __launch_bounds__(256) agg_kernel(
    const int* __restrict__ offF, const int* __restrict__ listF,
    const float* __restrict__ PaF, float* PbF, const float* __restrict__ b1F,
    const int* __restrict__ offR, const int* __restrict__ listR,
    const float* __restrict__ PaR, float* PbR, const float* __restrict__ b1R, int N)
{
    const int* off; const int* list; const float* Pa; float* Pb; const float* b1;
    if (blockIdx.y == 0) { off = offF; list = listF; Pa = PaF; Pb = PbF; b1 = b1F; }
    else                 { off = offR; list = listR; Pa = PaR; Pb = PbR; b1 = b1R; }
    int n = (blockIdx.x * 256 + threadIdx.x) >> 6;
    int lane = threadIdx.x & 63;
    if (n >= N) return;
    bool act = lane < 48;
    float sx = 0.f, sy = 0.f, ax = 0.f, ay = 0.f;
    long base = (long)n * 96 + 2 * lane;
    if (act) {
        sx = Pb[base] + b1[2 * lane];
        sy = Pb[base + 1] + b1[2 * lane + 1];
    }
    int beg = off[n], end = off[n + 1];
    for (int i = beg; i < end; ++i) {
        int src = list[i];                      // wave-uniform -> scalar load
        if (act) {
            float2 v = *(const float2*)(Pa + (long)src * 96 + 2 * lane);
            ax += fmaxf(v.x + sx, 0.f);
            ay += fmaxf(v.y + sy, 0.f);
        }
    }
    if (act) { Pb[base] = ax; Pb[base + 1] = ay; }
}

// ---------------- X = aggF@W2 + aggR@rW2 + degF*b2 + degR*rb2 (fused KI=192) ----------------
__global__ void __launch_bounds__(256) x_gemm(
    const float* __restrict__ AF, const float* __restrict__ AR,
    const float* __restrict__ W2, const float* __restrict__ rW2,
    const float* __restrict__ b2, const float* __restrict__ rb2,
    const int* __restrict__ offF, const int* __restrict__ offR,
    float* __restrict__ X, int N)
{
    __shared__ float tile[64][193];             // 193 % 32 == 1 -> conflict-free column reads
    int n0 = blockIdx.x * 64, tid = threadIdx.x;
    for (int idx = tid; idx < 64 * 96; idx += 256) {
        int r = idx / 96, c = idx % 96;
        int n = n0 + r;
        tile[r][c] = (n < N) ? AF[(long)n * 96 + c] : 0.f;
        tile[r][96 + c] = (n < N) ? AR[(long)n * 96 + c] : 0.f;
    }
    __syncthreads();
    int lane = tid & 63, w = tid >> 6;
    float acc[24];
#pragma unroll
    for (int c = 0; c < 24; ++c) acc[c] = 0.f;
    const float* WpF = W2 + w * 24;
    const float* WpR = rW2 + w * 24;
#pragma unroll 4
    for (int j = 0; j < 96; ++j) {
        float a = tile[lane][j];
#pragma unroll
        for (int c = 0; c < 24; ++c) acc[c] = fmaf(a, WpF[j * 96 + c], acc[c]);
    }
#pragma unroll 4
    for (int j = 0; j < 96; ++j) {
        float a = tile[lane][96 + j];
#pragma unroll
        for (int c = 0; c < 24; ++c) acc[c] = fmaf(a, WpR[j * 96 + c], acc[c]);
    }
    int n = n0 + lane;
    if (n >= N) return;
    float dF = (float)(offF[n + 1] - offF[n]);
    float dR = (float)(offR[n + 1] - offR[n]);
    float* outp = X + (long)n * 96 + w * 24;
#pragma unroll
    for (int c = 0; c < 24; ++c)
        outp[c] = acc[c] + dF * b2[w * 24 + c] + dR * rb2[w * 24 + c];
}

// ---------------- fused GRU: GI/GH never hit memory ----------------
__global__ void __launch_bounds__(256) gru_fused(
    const float* __restrict__ X, const float* __restrict__ h,
    const float* __restrict__ WihT, const float* __restrict__ WhhT,
    const float* __restrict__ bih, const float* __restrict__ bhh,
    float* __restrict__ hout, int N)
{
    __shared__ float xt[64][97];
    __shared__ float ht[64][33];
    int n0 = blockIdx.x * 64, tid = threadIdx.x;
    for (int idx = tid; idx < 64 * 96; idx += 256) {
        int r = idx / 96, c = idx % 96;
        int n = n0 + r;
        xt[r][c] = (n < N) ? X[(long)n * 96 + c] : 0.f;
    }
    for (int idx = tid; idx < 64 * 32; idx += 256) {
        int r = idx >> 5, c = idx & 31;
        int n = n0 + r;
        ht[r][c] = (n < N) ? h[(long)n * 32 + c] : 0.f;
    }
    __syncthreads();
    int lane = tid & 63, w = tid >> 6;
    int kb = w * 8;                             // 4 waves x 8 gate-cols = 32
    float ir[8], iz[8], in_[8], hr[8], hz[8], hn[8];
#pragma unroll
    for (int i = 0; i < 8; ++i) { ir[i] = iz[i] = in_[i] = hr[i] = hz[i] = hn[i] = 0.f; }
#pragma unroll 4
    for (int j = 0; j < 96; ++j) {
        float a = xt[lane][j];
        const float* Wr = WihT + j * 96;
#pragma unroll
        for (int i = 0; i < 8; ++i) {
            ir[i] = fmaf(a, Wr[kb + i], ir[i]);
            iz[i] = fmaf(a, Wr[32 + kb + i], iz[i]);
            in_[i] = fmaf(a, Wr[64 + kb + i], in_[i]);
        }
    }
#pragma unroll 4
    for (int j = 0; j < 32; ++j) {
        float b = ht[lane][j];
        const float* Wr = WhhT + j * 96;
#pragma unroll
        for (int i = 0; i < 8; ++i) {
            hr[i] = fmaf(b, Wr[kb + i], hr[i]);
            hz[i] = fmaf(b, Wr[32 + kb + i], hz[i]);
            hn[i] = fmaf(b, Wr[64 + kb + i], hn[i]);
        }
    }
    __syncthreads();                            // xt reads done; reuse cols 0..31 for h_new
#pragma unroll
    for (int i = 0; i < 8; ++i) {
        int k = kb + i;
        float r = 1.f / (1.f + __expf(-(ir[i] + bih[k] + hr[i] + bhh[k])));
        float z = 1.f / (1.f + __expf(-(iz[i] + bih[32 + k] + hz[i] + bhh[32 + k])));
        float nn = tanhf(in_[i] + bih[64 + k] + r * (hn[i] + bhh[64 + k]));
        xt[lane][k] = (1.f - z) * nn + z * ht[lane][k];
    }
    __syncthreads();
    for (int idx = tid; idx < 64 * 32; idx += 256) {
        int r = idx >> 5, c = idx & 31;
        int n = n0 + r;
        if (n < N) hout[(long)n * 32 + c] = xt[r][c];   // coalesced
    }
}

// ---------------- graph aggregator ----------------
__global__ void graph_agg(const float* __restrict__ h, const float* __restrict__ W1,
                          const float* __restrict__ b1, const int* __restrict__ gidx,
                          float* __restrict__ gs, int N, int chunk) {
    int k = threadIdx.x;  // 128
    int n_start = blockIdx.x * chunk;
    if (n_start >= N) return;
    int n_end = min(n_start + chunk, N);
    float acc = 0.f;
    int cur = gidx[n_start];
    for (int n = n_start; n < n_end; ++n) {
        int g = gidx[n];
        if (g != cur) { atomicAdd(&gs[cur * 128 + k], acc); acc = 0.f; cur = g; }
        float g1 = b1[k], g2 = b1[128 + k];
#pragma unroll 8
        for (int j = 0; j < 32; ++j) {
            float hv = h[(long)n * 32 + j];    // block-uniform -> scalar load
            g1 = fmaf(hv, W1[j * 256 + k], g1);
            g2 = fmaf(hv, W1[j * 256 + 128 + k], g2);
        }
        acc += (1.f / (1.f + __expf(-g1))) * g2;
    }
    atomicAdd(&gs[cur * 128 + k], acc);
}

__global__ void final_gemm(const float* __restrict__ gs, const float* __restrict__ W,
                           const float* __restrict__ b, float* __restrict__ out) {
    int g = blockIdx.x, k = threadIdx.x;  // 128 threads
    float a = b[k];
#pragma unroll 8
    for (int j = 0; j < 128; ++j) a = fmaf(gs[g * 128 + j], W[j * 128 + k], a);
    out[g * 128 + k] = a;
}

extern "C" void kernel_launch(void* const* d_in, const int* in_sizes, int n_in,
                              void* d_out, int out_size, void* d_ws, size_t ws_size,
                              hipStream_t stream) {
    const float* node_features = (const float*)d_in[0];
    const float* enc_W  = (const float*)d_in[1];
    const float* enc_b  = (const float*)d_in[2];
    const float* msg_W1 = (const float*)d_in[3];
    const float* msg_b1 = (const float*)d_in[4];
    const float* msg_W2 = (const float*)d_in[5];
    const float* msg_b2 = (const float*)d_in[6];
    const float* rmsg_W1 = (const float*)d_in[7];
    const float* rmsg_b1 = (const float*)d_in[8];
    const float* rmsg_W2 = (const float*)d_in[9];
    const float* rmsg_b2 = (const float*)d_in[10];
    const float* gru_Wih = (const float*)d_in[11];
    const float* gru_Whh = (const float*)d_in[12];
    const float* gru_bih = (const float*)d_in[13];
    const float* gru_bhh = (const float*)d_in[14];
    const float* agg_W1 = (const float*)d_in[15];
    const float* agg_b1 = (const float*)d_in[16];
    const float* agg_W2 = (const float*)d_in[17];
    const float* agg_b2 = (const float*)d_in[18];
    const int* from_idx = (const int*)d_in[19];
    const int* to_idx   = (const int*)d_in[20];
    const int* graph_idx = (const int*)d_in[21];

    const int N = in_sizes[0] / 32;
    const int E = in_sizes[19];
    const int NG = out_size / 128;
    float* out = (float*)d_out;

    char* ws = (char*)d_ws;
    auto alloc = [&](size_t b) { void* p = (void*)ws; ws += (b + 255) & ~(size_t)255; return p; };
    int* cnt_to   = (int*)alloc((size_t)N * 4);
    int* cnt_from = (int*)alloc((size_t)N * 4);
    int* off_to   = (int*)alloc((size_t)(N + 1) * 4);
    int* off_from = (int*)alloc((size_t)(N + 1) * 4);
    int* list_to  = (int*)alloc((size_t)E * 4);
    int* list_from= (int*)alloc((size_t)E * 4);
    float* h0  = (float*)alloc((size_t)N * 32 * 4);
    float* h1  = (float*)alloc((size_t)N * 32 * 4);
    float* PFa = (float*)alloc((size_t)N * 96 * 4);
    float* PFb = (float*)alloc((size_t)N * 96 * 4);
    float* PRa = (float*)alloc((size_t)N * 96 * 4);
    float* PRb = (float*)alloc((size_t)N * 96 * 4);
    float* WihT = (float*)alloc((size_t)3 * 96 * 96 * 4);
    float* WhhT = (float*)alloc((size_t)3 * 32 * 96 * 4);
    float* gs   = (float*)alloc((size_t)NG * 128 * 4);
    // rank arrays alias P-buffers (only live during CSR build, before any proj write)
    int* rank_to   = (int*)PFa;
    int* rank_from = (int*)PFb;

    hipMemsetAsync(cnt_to, 0, (size_t)N * 4, stream);
    hipMemsetAsync(cnt_from, 0, (size_t)N * 4, stream);
    hipMemsetAsync(gs, 0, (size_t)NG * 128 * 4, stream);

    int gE = (E + 255) / 256;
    count_rank_kernel<<<gE, 256, 0, stream>>>(from_idx, to_idx, cnt_to, cnt_from, rank_to, rank_from, E);
    scan2_kernel<<<2, 1024, 0, stream>>>(cnt_to, off_to, cnt_from, off_from, N);
    fill_kernel<<<gE, 256, 0, stream>>>(from_idx, to_idx, off_to, off_from, rank_to, rank_from,
                                        list_to, list_from, E);

    transpose_all<<<(3 * 96 * 96 + 3 * 32 * 96 + 255) / 256, 256, 0, stream>>>(gru_Wih, gru_Whh, WihT, WhhT);

    int gN64 = (N + 63) / 64;
    enc_gemm<<<gN64, 256, 0, stream>>>(node_features, enc_W, enc_b, h0, N);

    float* hcur = h0; float* hnext = h1;
    dim3 gProj(gN64, 2), gAgg((N + 3) / 4, 2);
    for (int l = 0; l < 3; ++l) {
        proj_kernel<<<gProj, 256, 0, stream>>>(hcur, msg_W1 + l * 6144, rmsg_W1 + l * 6144,
                                               PFa, PFb, PRa, PRb, N);
        agg_kernel<<<gAgg, 256, 0, stream>>>(off_to, list_to, PFa, PFb, msg_b1 + l * 96,
                                             off_from, list_from, PRa, PRb, rmsg_b1 + l * 96, N);
        float* X = PFa;
        x_gemm<<<gN64, 256, 0, stream>>>(PFb, PRb, msg_W2 + l * 9216, rmsg_W2 + l * 9216,
                                         msg_b2 + l * 96, rmsg_b2 + l * 96, off_to, off_from, X, N);
        gru_fused<<<gN64, 256, 0, stream>>>(X, hcur, WihT + l * 9216, WhhT + l * 3072,
                                            gru_bih + l * 96, gru_bhh + l * 96, hnext, N);
        float* t = hcur; hcur = hnext; hnext = t;
    }

    graph_agg<<<(N + 63) / 64, 128, 0, stream>>>(hcur, agg_W1, agg_b1, graph_idx, gs, N, 64);
    final_gemm<<<NG, 128, 0, stream>>>(gs, agg_W2, agg_b2, out);
}